// Round 5
// baseline (207.108 us; speedup 1.0000x reference)
//
#include <hip/hip_runtime.h>
#include <hip/hip_bf16.h>
#include <hip/hip_cooperative_groups.h>

namespace cg = cooperative_groups;

#define NPTS   131072
#define NNODES 2048
#define KSEL   32
#define TKNN   256                 // threads per knn block
#define PPT    2                   // points per thread (ILP)
#define PPG    (TKNN * PPT)        // 512 points per group
#define NGRP   (NPTS / PPG)        // 256 groups
#define NCHUNK 8                   // node chunks (block-uniform -> s_load)
#define CHN    (NNODES / NCHUNK)   // 256 nodes per chunk

typedef unsigned int uint;
typedef unsigned short u16;

// --- K0: pack nodes as float4 {x,y,z,|n|^2}, |n|^2 with numpy's mul-then-add rounding ---
__global__ __launch_bounds__(256) void prep_nodes(const float* __restrict__ nodes,
                                                  float4* __restrict__ n4) {
    int j = blockIdx.x * blockDim.x + threadIdx.x;
    if (j < NNODES) {
        float x = nodes[3 * j], y = nodes[3 * j + 1], z = nodes[3 * j + 2];
        float nn = __fadd_rn(__fadd_rn(__fmul_rn(x, x), __fmul_rn(y, y)), __fmul_rn(z, z));
        n4[j] = make_float4(x, y, z, nn);
    }
}

// --- K1: partial 1-NN, 2 points/thread (independent chains share each s_load) ---
// d2 = (pp + r) + nn where r = fma(-2p2,z, fma(-2p1,y, (-2p0)*x)) == -(2*dot) bit-exactly
// (scaling by -2 is exact at every step), so rounding matches the reference
// (pp - 2*dot) + nn with dot = fma(p2,z, fma(p1,y, p0*x)).
__global__ __launch_bounds__(256) void knn_part(const float* __restrict__ pts,
                                                const float4* __restrict__ n4,
                                                float* __restrict__ pbest,
                                                u16* __restrict__ pidx) {
    int bid = blockIdx.x;
    int c   = bid & (NCHUNK - 1);       // block-uniform chunk
    int g   = bid >> 3;                 // point group
    int t   = threadIdx.x;
    int pidA = g * PPG + t;
    int pidB = pidA + TKNN;

    float a0 = pts[3 * pidA], a1 = pts[3 * pidA + 1], a2 = pts[3 * pidA + 2];
    float b0 = pts[3 * pidB], b1 = pts[3 * pidB + 1], b2 = pts[3 * pidB + 2];
    float ppa = __fadd_rn(__fadd_rn(__fmul_rn(a0, a0), __fmul_rn(a1, a1)), __fmul_rn(a2, a2));
    float ppb = __fadd_rn(__fadd_rn(__fmul_rn(b0, b0), __fmul_rn(b1, b1)), __fmul_rn(b2, b2));
    // exact: -2 * p
    float na0 = __fmul_rn(-2.0f, a0), na1 = __fmul_rn(-2.0f, a1), na2 = __fmul_rn(-2.0f, a2);
    float nb0 = __fmul_rn(-2.0f, b0), nb1 = __fmul_rn(-2.0f, b1), nb2 = __fmul_rn(-2.0f, b2);

    const float4* np = n4 + c * CHN;    // block-uniform base -> scalar loads
    float bestA = 3.4e38f, bestB = 3.4e38f;
    int ia = 0, ib = 0;
    #pragma unroll 8
    for (int jj = 0; jj < CHN; ++jj) {
        float4 v = np[jj];
        float ra = __fmaf_rn(na2, v.z, __fmaf_rn(na1, v.y, __fmul_rn(na0, v.x)));
        float da = __fadd_rn(__fadd_rn(ppa, ra), v.w);
        float rb = __fmaf_rn(nb2, v.z, __fmaf_rn(nb1, v.y, __fmul_rn(nb0, v.x)));
        float db = __fadd_rn(__fadd_rn(ppb, rb), v.w);
        if (da < bestA) { bestA = da; ia = jj; }   // strict <: first occurrence wins
        if (db < bestB) { bestB = db; ib = jj; }
    }
    pbest[(size_t)c * NPTS + pidA] = bestA;
    pbest[(size_t)c * NPTS + pidB] = bestB;
    pidx [(size_t)c * NPTS + pidA] = (u16)(c * CHN + ia);
    pidx [(size_t)c * NPTS + pidB] = (u16)(c * CHN + ib);
}

// --- K2 (cooperative): merge partials + hist -> scan -> stable scatter, one launch ---
// grid = NGRP(256) blocks x 256 threads.
__global__ __launch_bounds__(256) void coop_tail(const float* __restrict__ pbest,
                                                 const u16* __restrict__ pidx,
                                                 int* __restrict__ pcd,
                                                 u16* __restrict__ hist16,
                                                 uint* __restrict__ offs,
                                                 float* __restrict__ out_d2,
                                                 float* __restrict__ out_id,
                                                 float* __restrict__ patch) {
    __shared__ uint smem[NNODES];       // phase A: counts; B: wave partials; C: ids
    cg::grid_group grid = cg::this_grid();
    int g = blockIdx.x, t = threadIdx.x;

    // ---- phase A: zero patch slice, merge 8 chunk-partials, LDS histogram ----
    patch[(size_t)g * 256 + t] = 0.0f;  // 256 blocks x 256 = 65536 floats zeroed
    for (int i = t; i < NNODES; i += 256) smem[i] = 0;
    __syncthreads();

    #pragma unroll
    for (int q = 0; q < PPT; ++q) {
        int pid = g * PPG + q * 256 + t;
        float b  = pbest[pid];
        int   bi = pidx[pid];
        #pragma unroll
        for (int c = 1; c < NCHUNK; ++c) {
            float v = pbest[(size_t)c * NPTS + pid];
            int   i = pidx [(size_t)c * NPTS + pid];
            if (v < b) { b = v; bi = i; }      // strict <: earlier chunk wins ties
        }
        atomicAdd(&smem[bi], 1u);
        out_d2[pid] = b;
        out_id[pid] = (float)bi;               // exact: bi < 2^24
        pcd[pid]    = bi;
    }
    __syncthreads();
    for (int i = t; i < NNODES; i += 256)
        hist16[(size_t)g * NNODES + i] = (u16)smem[i];   // count <= 512, fits u16

    grid.sync();

    // ---- phase B: exclusive prefix over the 256 groups, 8 nodes per block ----
    // thread t == source group t; block b covers nodes [8b, 8b+8)
    {
        int n0 = blockIdx.x * 8;
        int lane = t & 63, wv = t >> 6;     // 4 waves
        uint v[8], s[8];
        const uint4* row = (const uint4*)(hist16 + (size_t)t * NNODES + n0); // 16 B
        uint4 x0 = row[0];
        v[0] = x0.x & 0xffffu; v[1] = x0.x >> 16;
        v[2] = x0.y & 0xffffu; v[3] = x0.y >> 16;
        v[4] = x0.z & 0xffffu; v[5] = x0.z >> 16;
        v[6] = x0.w & 0xffffu; v[7] = x0.w >> 16;
        #pragma unroll
        for (int k = 0; k < 8; ++k) {
            uint a = v[k];
            #pragma unroll
            for (int d = 1; d < 64; d <<= 1) {
                uint y = __shfl_up(a, d, 64);
                if (lane >= d) a += y;
            }
            s[k] = a;                        // inclusive within wave
            if (lane == 63) smem[k * 4 + wv] = a;
        }
        __syncthreads();
        #pragma unroll
        for (int k = 0; k < 8; ++k) {
            uint off = 0;
            for (int w = 0; w < wv; ++w) off += smem[k * 4 + w];
            offs[(size_t)t * NNODES + n0 + k] = s[k] + off - v[k];  // exclusive
        }
    }

    grid.sync();

    // ---- phase C: stable scatter of first-32 point indices per node ----
    __syncthreads();                        // reuse smem as ids[512]
    int* ids = (int*)smem;
    #pragma unroll
    for (int q = 0; q < PPT; ++q)
        ids[q * 256 + t] = pcd[g * PPG + q * 256 + t];
    __syncthreads();

    int i0 = t, i1 = 256 + t;
    int my0 = ids[i0], my1 = ids[i1];
    int r0 = 0, r1 = 0;
    #pragma unroll 8
    for (int j = 0; j < PPG; ++j) {
        int id = ids[j];                     // broadcast read, conflict-free
        r0 += (j < i0 && id == my0) ? 1 : 0;
        r1 += (j < i1 && id == my1) ? 1 : 0;
    }
    uint rk0 = offs[(size_t)g * NNODES + my0] + (uint)r0;
    uint rk1 = offs[(size_t)g * NNODES + my1] + (uint)r1;
    if (rk0 < KSEL) patch[(size_t)my0 * KSEL + rk0] = (float)(g * PPG + i0);
    if (rk1 < KSEL) patch[(size_t)my1 * KSEL + rk1] = (float)(g * PPG + i1);
}

extern "C" void kernel_launch(void* const* d_in, const int* in_sizes, int n_in,
                              void* d_out, int out_size, void* d_ws, size_t ws_size,
                              hipStream_t stream) {
    const float* pts   = (const float*)d_in[0];
    const float* nodes = (const float*)d_in[1];

    float* out       = (float*)d_out;
    float* out_d2    = out;                 // 131072 floats
    float* out_id    = out + NPTS;          // 131072 floats
    float* out_patch = out + 2 * NPTS;      // 65536 floats

    // workspace layout (7.5 MB): offs overlays pbest (dead after phase A, written after grid.sync)
    char* ws = (char*)d_ws;
    float* pbest  = (float*)ws;                               // 4 MB  (8 x 131072 f32)
    uint*  offs   = (uint*) ws;                               // 2 MB  (256 x 2048 u32) overlay
    u16*   pidx   = (u16*) (ws + (4 << 20));                  // 2 MB  (8 x 131072 u16)
    int*   pcd    = (int*) (ws + (6 << 20));                  // 512 KB
    u16*   hist16 = (u16*) (ws + (6 << 20) + (512 << 10));    // 1 MB  (256 x 2048 u16)
    float4* n4    = (float4*)(ws + (7 << 20) + (512 << 10));  // 32 KB

    prep_nodes<<<(NNODES + 255) / 256, 256, 0, stream>>>(nodes, n4);
    knn_part<<<NGRP * NCHUNK, TKNN, 0, stream>>>(pts, n4, pbest, pidx);

    void* args[] = { (void*)&pbest, (void*)&pidx, (void*)&pcd, (void*)&hist16,
                     (void*)&offs, (void*)&out_d2, (void*)&out_id, (void*)&out_patch };
    hipLaunchCooperativeKernel((void*)coop_tail, dim3(NGRP), dim3(256), args, 0, stream);
}

// Round 6
// 131.520 us; speedup vs baseline: 1.5747x; 1.5747x over previous
//
#include <hip/hip_runtime.h>
#include <hip/hip_bf16.h>

#define NPTS   131072
#define NNODES 2048
#define KSEL   32
#define TKNN   256                 // threads per knn block
#define PPT    2                   // points per thread (ILP)
#define PPG    (TKNN * PPT)        // 512 points per group
#define NGRP   (NPTS / PPG)        // 256 groups
#define NCHUNK 8                   // node chunks (block-uniform -> s_load)
#define CHN    (NNODES / NCHUNK)   // 256 nodes per chunk

typedef unsigned int uint;
typedef unsigned short u16;
typedef unsigned long long u64;

// order-preserving fp32 -> u32 (handles the tiny-negative cancellation case)
__device__ __forceinline__ uint f2ord(float d) {
    uint b = __float_as_uint(d);
    return (b & 0x80000000u) ? ~b : (b | 0x80000000u);
}
__device__ __forceinline__ float ord2f(uint t) {
    uint b = (t & 0x80000000u) ? (t ^ 0x80000000u) : ~t;
    return __uint_as_float(b);
}

// --- K0: init knnres to +inf keys; first 2048 threads also pack nodes {x,y,z,|n|^2} ---
__global__ __launch_bounds__(256) void prep_init(const float* __restrict__ nodes,
                                                 float4* __restrict__ n4,
                                                 u64* __restrict__ knnres) {
    int i = blockIdx.x * 256 + threadIdx.x;
    knnres[i] = ~0ull;                       // max key
    if (i < NNODES) {
        float x = nodes[3 * i], y = nodes[3 * i + 1], z = nodes[3 * i + 2];
        // |n|^2 with numpy's mul-then-add rounding
        float nn = __fadd_rn(__fadd_rn(__fmul_rn(x, x), __fmul_rn(y, y)), __fmul_rn(z, z));
        n4[i] = make_float4(x, y, z, nn);
    }
}

// --- K1: partial 1-NN, 2 pts/thread; chunks merge via u64 atomicMin (d2, idx) key ---
// d2 = (pp + r) + nn, r = fma(-2p2,z, fma(-2p1,y, (-2p0)*x)) == -(2*dot) bit-exactly,
// matching the reference (pp - 2*dot) + nn, dot = fma(p2,z, fma(p1,y, p0*x)).
__global__ __launch_bounds__(256) void knn_part(const float* __restrict__ pts,
                                                const float4* __restrict__ n4,
                                                u64* __restrict__ knnres) {
    int bid = blockIdx.x;
    int c   = bid & (NCHUNK - 1);            // block-uniform chunk
    int g   = bid >> 3;                      // point group
    int t   = threadIdx.x;
    int pidA = g * PPG + t;
    int pidB = pidA + TKNN;

    float a0 = pts[3 * pidA], a1 = pts[3 * pidA + 1], a2 = pts[3 * pidA + 2];
    float b0 = pts[3 * pidB], b1 = pts[3 * pidB + 1], b2 = pts[3 * pidB + 2];
    float ppa = __fadd_rn(__fadd_rn(__fmul_rn(a0, a0), __fmul_rn(a1, a1)), __fmul_rn(a2, a2));
    float ppb = __fadd_rn(__fadd_rn(__fmul_rn(b0, b0), __fmul_rn(b1, b1)), __fmul_rn(b2, b2));
    float na0 = __fmul_rn(-2.0f, a0), na1 = __fmul_rn(-2.0f, a1), na2 = __fmul_rn(-2.0f, a2);
    float nb0 = __fmul_rn(-2.0f, b0), nb1 = __fmul_rn(-2.0f, b1), nb2 = __fmul_rn(-2.0f, b2);

    const float4* np = n4 + c * CHN;         // block-uniform base -> scalar s_load
    float bestA = 3.4e38f, bestB = 3.4e38f;
    int ia = 0, ib = 0;
    #pragma unroll 8
    for (int jj = 0; jj < CHN; ++jj) {
        float4 v = np[jj];
        float ra = __fmaf_rn(na2, v.z, __fmaf_rn(na1, v.y, __fmul_rn(na0, v.x)));
        float da = __fadd_rn(__fadd_rn(ppa, ra), v.w);
        float rb = __fmaf_rn(nb2, v.z, __fmaf_rn(nb1, v.y, __fmul_rn(nb0, v.x)));
        float db = __fadd_rn(__fadd_rn(ppb, rb), v.w);
        if (da < bestA) { bestA = da; ia = jj; }   // strict <: first occurrence wins
        if (db < bestB) { bestB = db; ib = jj; }
    }
    u64 keyA = ((u64)f2ord(bestA) << 32) | (uint)(c * CHN + ia);
    u64 keyB = ((u64)f2ord(bestB) << 32) | (uint)(c * CHN + ib);
    atomicMin(&knnres[pidA], keyA);          // min key == (min d2, then min idx)
    atomicMin(&knnres[pidB], keyB);
}

// --- K2: decode winners, write d2/id/pcd outputs, per-group u16 histogram, zero patch ---
__global__ __launch_bounds__(256) void merge_hist(const u64* __restrict__ knnres,
                                                  float* __restrict__ out_d2,
                                                  float* __restrict__ out_id,
                                                  int* __restrict__ pcd,
                                                  u16* __restrict__ hist16,
                                                  float* __restrict__ patch) {
    __shared__ uint lh[NNODES];
    int g = blockIdx.x, t = threadIdx.x;
    patch[(size_t)g * 256 + t] = 0.0f;       // 256x256 = full 65536-float patch zeroed
    for (int i = t; i < NNODES; i += 256) lh[i] = 0;
    __syncthreads();

    #pragma unroll
    for (int q = 0; q < PPT; ++q) {
        int pid = g * PPG + q * 256 + t;
        u64 key = knnres[pid];
        uint bi = (uint)key;                 // low 32: node index
        float d = ord2f((uint)(key >> 32));  // exact d2 decode
        atomicAdd(&lh[bi], 1u);
        out_d2[pid] = d;
        out_id[pid] = (float)bi;             // exact: bi < 2^24
        pcd[pid]    = (int)bi;
    }
    __syncthreads();
    for (int i = t; i < NNODES; i += 256)
        hist16[(size_t)g * NNODES + i] = (u16)lh[i];   // contiguous 512B stores
}

// --- K3: per-node exclusive prefix across the 256 groups; offs in [node][group] ---
// 512 blocks x 256 thr = 4 waves; wave wv handles node bid*4+wv; lane l -> groups 4l..4l+3.
__global__ __launch_bounds__(256) void scan_offs(const u16* __restrict__ hist16,
                                                 uint* __restrict__ offs) {
    int t = threadIdx.x, lane = t & 63, wv = t >> 6;
    int node = blockIdx.x * 4 + wv;

    uint v0 = hist16[(size_t)(4 * lane + 0) * NNODES + node];
    uint v1 = hist16[(size_t)(4 * lane + 1) * NNODES + node];
    uint v2 = hist16[(size_t)(4 * lane + 2) * NNODES + node];
    uint v3 = hist16[(size_t)(4 * lane + 3) * NNODES + node];
    uint s = v0 + v1 + v2 + v3;
    uint a = s;
    #pragma unroll
    for (int d = 1; d < 64; d <<= 1) {
        uint y = __shfl_up(a, d, 64);
        if (lane >= d) a += y;
    }
    uint base = a - s;                        // exclusive across lanes
    uint4 o = make_uint4(base, base + v0, base + v0 + v1, base + v0 + v1 + v2);
    *(uint4*)(offs + (size_t)node * NGRP + 4 * lane) = o;   // contiguous 16B store
}

// --- K4: stable scatter of first-32 point indices per node ---
__global__ __launch_bounds__(256) void scatter_patch(const int* __restrict__ pcd,
                                                     const uint* __restrict__ offs,
                                                     float* __restrict__ patch) {
    __shared__ int ids[PPG];
    int g = blockIdx.x, t = threadIdx.x;
    ids[t]       = pcd[g * PPG + t];
    ids[256 + t] = pcd[g * PPG + 256 + t];
    __syncthreads();

    int i0 = t, i1 = 256 + t;
    int my0 = ids[i0], my1 = ids[i1];
    int r0 = 0, r1 = 0;
    #pragma unroll 8
    for (int j = 0; j < PPG; ++j) {
        int id = ids[j];                      // broadcast LDS read, conflict-free
        r0 += (j < i0 && id == my0) ? 1 : 0;
        r1 += (j < i1 && id == my1) ? 1 : 0;
    }
    uint rk0 = offs[(size_t)my0 * NGRP + g] + (uint)r0;
    uint rk1 = offs[(size_t)my1 * NGRP + g] + (uint)r1;
    if (rk0 < KSEL) patch[(size_t)my0 * KSEL + rk0] = (float)(g * PPG + i0);
    if (rk1 < KSEL) patch[(size_t)my1 * KSEL + rk1] = (float)(g * PPG + i1);
}

extern "C" void kernel_launch(void* const* d_in, const int* in_sizes, int n_in,
                              void* d_out, int out_size, void* d_ws, size_t ws_size,
                              hipStream_t stream) {
    const float* pts   = (const float*)d_in[0];
    const float* nodes = (const float*)d_in[1];

    float* out       = (float*)d_out;
    float* out_d2    = out;                  // 131072 floats
    float* out_id    = out + NPTS;           // 131072 floats
    float* out_patch = out + 2 * NPTS;       // 65536 floats

    // workspace: 4.6 MB
    char* ws = (char*)d_ws;
    u64*   knnres = (u64*) ws;                               // 1 MB   (131072 x u64)
    u16*   hist16 = (u16*) (ws + (1 << 20));                 // 1 MB   (256 x 2048 u16)
    uint*  offs   = (uint*) (ws + (2 << 20));                // 2 MB   (2048 x 256 u32)
    int*   pcd    = (int*)  (ws + (4 << 20));                // 512 KB
    float4* n4    = (float4*)(ws + (4 << 20) + (512 << 10)); // 32 KB

    prep_init<<<NPTS / 256, 256, 0, stream>>>(nodes, n4, knnres);
    knn_part<<<NGRP * NCHUNK, TKNN, 0, stream>>>(pts, n4, knnres);
    merge_hist<<<NGRP, 256, 0, stream>>>(knnres, out_d2, out_id, pcd, hist16, out_patch);
    scan_offs<<<NNODES / 4, 256, 0, stream>>>(hist16, offs);
    scatter_patch<<<NGRP, 256, 0, stream>>>(pcd, offs, out_patch);
}